// Round 10
// baseline (195.360 us; speedup 1.0000x reference)
//
#include <hip/hip_runtime.h>
#include <hip/hip_bf16.h>
#include <hip/hip_cooperative_groups.h>

namespace cg = cooperative_groups;

// Mamba block: B=4, L=512, D_MODEL=128, D_INNER=D_STATE=256
// launch 1: proj (MFMA) + weight-prep blocks
// launch 2: cooperative fused {dbc GEMM -> scan1 -> scan2 -> scan3 -> out GEMM}
//           (falls back to 5 separate launches if cooperative launch fails)

#define MROWS 2048
#define DM 128
#define DI 256
#define DS 256
#define LLEN 512
#define LC 64
#define NC 8

#define LOG2E 1.44269504088896340736f

typedef short bf16x8 __attribute__((ext_vector_type(8)));
typedef float f32x4  __attribute__((ext_vector_type(4)));

__device__ __forceinline__ short f2bf(float f) {
    union { float f; unsigned u; } v; v.f = f;
    unsigned r = v.u + 0x7FFFu + ((v.u >> 16) & 1u);   // RNE
    return (short)(r >> 16);
}

// Taylor-2 exp(a*dl): |a*dl| <= ~0.04 -> rel err < 1e-5
#define TEXP2(c1, c2, dl) fmaf(fmaf((c2), (dl), (c1)), (dl), 1.f)

// ---------------------------------------------------------------------------
// 32x32 transpose+convert tile (fp32 src -> bf16 dst, dst N-major)
// ---------------------------------------------------------------------------
__device__ __forceinline__ void tconv(float (*tile)[33],
                                      const float* __restrict__ src,
                                      short* __restrict__ dst,
                                      int Ms, int Ns, int ti, int tj, int tid)
{
    const int r = tid >> 5, c = tid & 31;
#pragma unroll
    for (int i = 0; i < 4; ++i)
        tile[r + 8 * i][c] = src[(size_t)(ti * 32 + r + 8 * i) * Ns + tj * 32 + c];
    __syncthreads();
#pragma unroll
    for (int i = 0; i < 4; ++i)
        dst[(size_t)(tj * 32 + r + 8 * i) * Ms + ti * 32 + c] = f2bf(tile[c][r + 8 * i]);
}

// ---------------------------------------------------------------------------
// launch 1: in_proj (MFMA) + fused weight-prep blocks  (grid 15x32, 256 thr)
// ---------------------------------------------------------------------------
__global__ __launch_bounds__(256) void k_proj_mfma(
    const float* __restrict__ x, const float* __restrict__ W_in,
    const float* __restrict__ Wd, const float* __restrict__ Wb,
    const float* __restrict__ Wc, const float* __restrict__ W_out,
    float* __restrict__ xs, short* __restrict__ xs_bf, float* __restrict__ sz,
    short* __restrict__ WdbcT, short* __restrict__ W_outT)
{
    const int t = threadIdx.x;

    if (blockIdx.x >= 8) {               // ---- prep role: 224 tiles ----
        __shared__ float tile[32][33];
        const int uu = (blockIdx.x - 8) * 32 + blockIdx.y;
        if (uu < 64)       tconv(tile, Wd,    WdbcT,                       256, 256, uu & 7,         uu >> 3,         t);
        else if (uu < 128) tconv(tile, Wb,    WdbcT + (size_t)256 * 256,   256, 256, (uu - 64) & 7,  (uu - 64) >> 3,  t);
        else if (uu < 192) tconv(tile, Wc,    WdbcT + (size_t)512 * 256,   256, 256, (uu - 128) & 7, (uu - 128) >> 3, t);
        else if (uu < 224) tconv(tile, W_out, W_outT,                      256, 128, (uu - 192) & 7, (uu - 192) >> 3, t);
        return;
    }

    // ---- GEMM role ----
    __shared__ short As[64][136];
    __shared__ short Bs[64][136];
    f32x4 acc[4] = {};
    const int w = t >> 6, lane = t & 63;
    const int srow = t >> 2, sseg = t & 3;
    const int frow = lane & 15, fk = (lane >> 4) << 3;
    const int r0 = blockIdx.y * 64, n0 = blockIdx.x * 64;

    {
        const float* ap = x + (size_t)(r0 + srow) * DM + sseg * 32;
        short tmp[32];
#pragma unroll
        for (int j = 0; j < 8; ++j) {
            float4 f = *(const float4*)(ap + j * 4);
            tmp[j * 4 + 0] = f2bf(f.x); tmp[j * 4 + 1] = f2bf(f.y);
            tmp[j * 4 + 2] = f2bf(f.z); tmp[j * 4 + 3] = f2bf(f.w);
        }
#pragma unroll
        for (int m = 0; m < 4; ++m)
            *(bf16x8*)&As[srow][sseg * 32 + m * 8] = *(bf16x8*)&tmp[m * 8];
    }
    {
#pragma unroll
        for (int i = 0; i < 32; i += 2) {
            const int k = sseg * 32 + i;
            float f0 = W_in[(size_t)k * 512 + n0 + srow];
            float f1 = W_in[(size_t)(k + 1) * 512 + n0 + srow];
            unsigned pk = (unsigned short)f2bf(f0) | ((unsigned)(unsigned short)f2bf(f1) << 16);
            *(unsigned*)&Bs[srow][k] = pk;
        }
    }
    __syncthreads();

#pragma unroll
    for (int kk = 0; kk < 128; kk += 32) {
        bf16x8 af = *(const bf16x8*)&As[w * 16 + frow][kk + fk];
#pragma unroll
        for (int ct = 0; ct < 4; ++ct) {
            bf16x8 bfr = *(const bf16x8*)&Bs[ct * 16 + frow][kk + fk];
            acc[ct] = __builtin_amdgcn_mfma_f32_16x16x32_bf16(af, bfr, acc[ct], 0, 0, 0);
        }
    }

    const int rr = r0 + w * 16 + (lane >> 4) * 4;
    const int c0 = n0 + (lane & 15);
#pragma unroll
    for (int ct = 0; ct < 4; ++ct) {
        const int c = c0 + ct * 16;
#pragma unroll
        for (int rg = 0; rg < 4; ++rg) {
            const float v = acc[ct][rg];
            const int r = rr + rg;
            if (c < DI) {
                xs[(size_t)r * DI + c]    = v;
                xs_bf[(size_t)r * DI + c] = f2bf(v);
            } else {
                sz[(size_t)r * DI + (c - DI)] = v / (1.f + __expf(-v));
            }
        }
    }
}

// ===========================================================================
// Fused phases (512-thread blocks). Shared by cooperative + fallback paths.
// ===========================================================================

// ---- phase 0: dbc GEMM. 192 active blocks, tile 64r x 128c, K=256 ----------
__device__ __forceinline__ void phase_dbc(
    int blk, int t,
    const short* __restrict__ xs_bf, const short* __restrict__ WdbcT,
    const float* __restrict__ xs,
    float* __restrict__ dlt, float* __restrict__ u, float* __restrict__ cvv,
    short (*As)[72], short (*Bs)[72])
{
    if (blk >= 192) return;
    const int w8 = t >> 6, lane = t & 63;
    const int rf = w8 & 3, ch = w8 >> 2;
    const int frow = lane & 15, fk = (lane >> 4) << 3;
    const int bx = blk % 6, by = blk / 6;
    const int r0 = by * 64, n0 = bx * 128;
    const int arow = t >> 3, ak = (t & 7) * 8;
    const int brow = t >> 2, bk = (t & 3) * 16;
    f32x4 acc[4] = {};

    for (int k0 = 0; k0 < DI; k0 += 64) {
        bf16x8 a0 = *(const bf16x8*)(xs_bf + (size_t)(r0 + arow) * DI + k0 + ak);
        bf16x8 b0 = *(const bf16x8*)(WdbcT + (size_t)(n0 + brow) * DI + k0 + bk);
        bf16x8 b1 = *(const bf16x8*)(WdbcT + (size_t)(n0 + brow) * DI + k0 + bk + 8);
        __syncthreads();
        *(bf16x8*)&As[arow][ak]     = a0;
        *(bf16x8*)&Bs[brow][bk]     = b0;
        *(bf16x8*)&Bs[brow][bk + 8] = b1;
        __syncthreads();
#pragma unroll
        for (int kk = 0; kk < 64; kk += 32) {
            bf16x8 af = *(const bf16x8*)&As[rf * 16 + frow][kk + fk];
#pragma unroll
            for (int ct = 0; ct < 4; ++ct) {
                bf16x8 bfr = *(const bf16x8*)&Bs[(ch * 4 + ct) * 16 + frow][kk + fk];
                acc[ct] = __builtin_amdgcn_mfma_f32_16x16x32_bf16(af, bfr, acc[ct], 0, 0, 0);
            }
        }
    }

    const int rr = r0 + rf * 16 + (lane >> 4) * 4;
    const int nbase = n0 + ch * 64;
    const int wsel = nbase >> 8;          // 0: delta, 1: B, 2: C
    const int nb = nbase & 255;
#pragma unroll
    for (int ct = 0; ct < 4; ++ct) {
        const int c = nb + ct * 16 + (lane & 15);
#pragma unroll
        for (int rg = 0; rg < 4; ++rg) {
            const float v = acc[ct][rg];
            const size_t idx = (size_t)(rr + rg) * DI + c;
            if (wsel == 0)      dlt[idx] = v;
            else if (wsel == 1) u[idx]   = v * xs[idx];   // Bv * xs
            else                cvv[idx] = v;
        }
    }
}

// ---- phase 1: chunk-local states. 256 blocks x 8 waves = 2048 units --------
__device__ __forceinline__ void phase_scan1(
    int blk, int t,
    const float* __restrict__ dlt, const float* __restrict__ u,
    const float* __restrict__ Aa,
    float* __restrict__ tc, float* __restrict__ dsm,
    float (*dls)[4][LC])
{
    const int w8 = t >> 6, lane = t & 63;
    const int b = blk & 3, c = (blk >> 2) & 7;
    const int d0 = ((blk >> 5) * 8 + w8) * 4;
    const size_t base = (size_t)b * LLEN * DI + (size_t)c * LC * DI;

    float4 dv = *(const float4*)(dlt + base + (size_t)lane * DI + d0);
    dls[w8][0][lane] = dv.x;
    dls[w8][1][lane] = dv.y;
    dls[w8][2][lane] = dv.z;
    dls[w8][3][lane] = dv.w;
    float dsv[4] = { dv.x, dv.y, dv.z, dv.w };
#pragma unroll
    for (int dd = 0; dd < 4; ++dd) {
#pragma unroll
        for (int off = 32; off > 0; off >>= 1)
            dsv[dd] += __shfl_xor(dsv[dd], off);
    }

    float4 c1[4], c2[4];
#pragma unroll
    for (int dd = 0; dd < 4; ++dd) {
        float4 a = *(const float4*)(Aa + (size_t)(d0 + dd) * DS + lane * 4);
        c1[dd] = a;
        c2[dd] = make_float4(0.5f * a.x * a.x, 0.5f * a.y * a.y,
                             0.5f * a.z * a.z, 0.5f * a.w * a.w);
    }

    const float4* up = (const float4*)(u + base) + lane;
    float4 s[4] = {};
    for (int g = 0; g < LC / 4; ++g) {
        float4 uv[4];
#pragma unroll
        for (int i = 0; i < 4; ++i)
            uv[i] = up[(size_t)(g * 4 + i) * 64];
#pragma unroll
        for (int i = 0; i < 4; ++i) {
            const int l = g * 4 + i;
#pragma unroll
            for (int dd = 0; dd < 4; ++dd) {
                const float dl = dls[w8][dd][l];
                s[dd].x = fmaf(TEXP2(c1[dd].x, c2[dd].x, dl), s[dd].x, dl * uv[i].x);
                s[dd].y = fmaf(TEXP2(c1[dd].y, c2[dd].y, dl), s[dd].y, dl * uv[i].y);
                s[dd].z = fmaf(TEXP2(c1[dd].z, c2[dd].z, dl), s[dd].z, dl * uv[i].z);
                s[dd].w = fmaf(TEXP2(c1[dd].w, c2[dd].w, dl), s[dd].w, dl * uv[i].w);
            }
        }
    }

    const size_t rbb = ((size_t)(b * 256 + d0)) * NC + c;
#pragma unroll
    for (int dd = 0; dd < 4; ++dd) {
        *(float4*)(tc + (rbb + (size_t)dd * NC) * 256 + lane * 4) = s[dd];
        if (lane == 0) dsm[rbb + dd * NC] = dsv[dd];
    }
}

// ---- phase 2: combine chunk boundaries. EXACTLY 1024 units (w8<4) ----------
__device__ __forceinline__ void phase_scan2(
    int blk, int t, const float* __restrict__ Aa,
    float* __restrict__ tc, const float* __restrict__ dsm)
{
    const int w8 = t >> 6, lane = t & 63;
    if (w8 >= 4) return;
    const int idx = blk * 4 + w8;         // 0..1023
    const int b2 = idx & 3;
    const int d2 = idx >> 2;              // 0..255

    float4 a4 = *(const float4*)(Aa + (size_t)d2 * DS + lane * 4);
    a4.x *= LOG2E; a4.y *= LOG2E; a4.z *= LOG2E; a4.w *= LOG2E;

    const size_t rb = ((size_t)(b2 * 256 + d2)) * NC;
    float4 Tr[NC];
    float  Dc[NC];
#pragma unroll
    for (int cc = 0; cc < NC; ++cc) {
        Tr[cc] = *(const float4*)(tc + (rb + cc) * 256 + lane * 4);
        Dc[cc] = dsm[rb + cc];
    }
    float4 s = make_float4(0.f, 0.f, 0.f, 0.f);
#pragma unroll
    for (int cc = 0; cc < NC; ++cc) {
        float4 tmp = Tr[cc];
        Tr[cc] = s;                        // s_init[c]
        s.x = exp2f(a4.x * Dc[cc]) * s.x + tmp.x;
        s.y = exp2f(a4.y * Dc[cc]) * s.y + tmp.y;
        s.z = exp2f(a4.z * Dc[cc]) * s.z + tmp.z;
        s.w = exp2f(a4.w * Dc[cc]) * s.w + tmp.w;
    }
#pragma unroll
    for (int cc = 0; cc < NC; ++cc)
        *(float4*)(tc + (rb + cc) * 256 + lane * 4) = Tr[cc];
}

// ---- phase 3: outputs from s_init. flush T every 4 steps -------------------
__device__ __forceinline__ void phase_scan3(
    int blk, int t,
    const float* __restrict__ dlt, const float* __restrict__ u,
    const float* __restrict__ cvv, const float* __restrict__ Aa,
    const float* __restrict__ tc, float* __restrict__ yv,
    float (*dls)[4][LC], float (*T)[LC][17])
{
    const int w8 = t >> 6, lane = t & 63;
    const int b = blk & 3, c = (blk >> 2) & 7;
    const int d0 = ((blk >> 5) * 8 + w8) * 4;
    const size_t base = (size_t)b * LLEN * DI + (size_t)c * LC * DI;

    float4 dv = *(const float4*)(dlt + base + (size_t)lane * DI + d0);
    dls[w8][0][lane] = dv.x;
    dls[w8][1][lane] = dv.y;
    dls[w8][2][lane] = dv.z;
    dls[w8][3][lane] = dv.w;

    float4 c1[4], c2[4];
#pragma unroll
    for (int dd = 0; dd < 4; ++dd) {
        float4 a = *(const float4*)(Aa + (size_t)(d0 + dd) * DS + lane * 4);
        c1[dd] = a;
        c2[dd] = make_float4(0.5f * a.x * a.x, 0.5f * a.y * a.y,
                             0.5f * a.z * a.z, 0.5f * a.w * a.w);
    }

    const float4* up = (const float4*)(u + base) + lane;
    const float4* cp = (const float4*)(cvv + base) + lane;
    float* yb = yv + base;

    const size_t rbb = ((size_t)(b * 256 + d0)) * NC + c;
    float4 s[4];
#pragma unroll
    for (int dd = 0; dd < 4; ++dd)
        s[dd] = *(const float4*)(tc + (rbb + (size_t)dd * NC) * 256 + lane * 4);

    const int col = lane & 15, seg = lane >> 4;

    for (int g = 0; g < LC / 4; ++g) {
        float4 uv[4], cV[4];
#pragma unroll
        for (int i = 0; i < 4; ++i) {
            uv[i] = up[(size_t)(g * 4 + i) * 64];
            cV[i] = cp[(size_t)(g * 4 + i) * 64];
        }
#pragma unroll
        for (int i = 0; i < 4; ++i) {
            const int l = g * 4 + i;
#pragma unroll
            for (int dd = 0; dd < 4; ++dd) {
                const float dl = dls[w8][dd][l];
                s[dd].x = fmaf(TEXP2(c1[dd].x, c2[dd].x, dl), s[dd].x, dl * uv[i].x);
                s[dd].y = fmaf(TEXP2(c1[dd].y, c2[dd].y, dl), s[dd].y, dl * uv[i].y);
                s[dd].z = fmaf(TEXP2(c1[dd].z, c2[dd].z, dl), s[dd].z, dl * uv[i].z);
                s[dd].w = fmaf(TEXP2(c1[dd].w, c2[dd].w, dl), s[dd].w, dl * uv[i].w);
                T[w8][lane][dd * 4 + i] =
                    fmaf(s[dd].w, cV[i].w, fmaf(s[dd].z, cV[i].z,
                         fmaf(s[dd].y, cV[i].y, s[dd].x * cV[i].x)));
            }
        }
        // flush 4 steps: 16 cols x 64 rows; 4 lanes per column
        float sm = 0.f;
#pragma unroll
        for (int r = 0; r < 16; ++r)
            sm += T[w8][seg * 16 + r][col];
        sm += __shfl_xor(sm, 16);
        sm += __shfl_xor(sm, 32);
        if (lane < 16)
            yb[(size_t)(g * 4 + (col & 3)) * DI + d0 + (col >> 2)] = sm;
    }
}

// ---- phase 4: out GEMM. 32 active blocks, tile 64r x 128c, K=256 -----------
__device__ __forceinline__ void phase_out(
    int blk, int t,
    const float* __restrict__ yv, const float* __restrict__ szp,
    const short* __restrict__ W_outT, float* __restrict__ out,
    short (*As)[72], short (*Bs)[72])
{
    if (blk >= 32) return;
    const int w8 = t >> 6, lane = t & 63;
    const int rf = w8 & 3, ch = w8 >> 2;
    const int frow = lane & 15, fk = (lane >> 4) << 3;
    const int r0 = blk * 64;
    const int arow = t >> 3, ak = (t & 7) * 8;
    const int brow = t >> 2, bk = (t & 3) * 16;
    f32x4 acc[4] = {};

    for (int k0 = 0; k0 < DI; k0 += 64) {
        const size_t aoff = (size_t)(r0 + arow) * DI + k0 + ak;
        float4 y0 = *(const float4*)(yv + aoff);
        float4 y1 = *(const float4*)(yv + aoff + 4);
        float4 s0 = *(const float4*)(szp + aoff);
        float4 s1 = *(const float4*)(szp + aoff + 4);
        bf16x8 a0;
        a0[0] = f2bf(y0.x * s0.x); a0[1] = f2bf(y0.y * s0.y);
        a0[2] = f2bf(y0.z * s0.z); a0[3] = f2bf(y0.w * s0.w);
        a0[4] = f2bf(y1.x * s1.x); a0[5] = f2bf(y1.y * s1.y);
        a0[6] = f2bf(y1.z * s1.z); a0[7] = f2bf(y1.w * s1.w);
        bf16x8 b0 = *(const bf16x8*)(W_outT + (size_t)brow * DI + k0 + bk);
        bf16x8 b1 = *(const bf16x8*)(W_outT + (size_t)brow * DI + k0 + bk + 8);
        __syncthreads();
        *(bf16x8*)&As[arow][ak]     = a0;
        *(bf16x8*)&Bs[brow][bk]     = b0;
        *(bf16x8*)&Bs[brow][bk + 8] = b1;
        __syncthreads();
#pragma unroll
        for (int kk = 0; kk < 64; kk += 32) {
            bf16x8 af = *(const bf16x8*)&As[rf * 16 + frow][kk + fk];
#pragma unroll
            for (int ct = 0; ct < 4; ++ct) {
                bf16x8 bfr = *(const bf16x8*)&Bs[(ch * 4 + ct) * 16 + frow][kk + fk];
                acc[ct] = __builtin_amdgcn_mfma_f32_16x16x32_bf16(af, bfr, acc[ct], 0, 0, 0);
            }
        }
    }

    const int rr = r0 + rf * 16 + (lane >> 4) * 4;
#pragma unroll
    for (int ct = 0; ct < 4; ++ct) {
        const int c = ch * 64 + ct * 16 + (lane & 15);
#pragma unroll
        for (int rg = 0; rg < 4; ++rg)
            out[(size_t)(rr + rg) * DM + c] = acc[ct][rg];
    }
}

// ---------------------- cooperative fused kernel ----------------------------
__global__ __launch_bounds__(512, 2) void k_fused(
    const short* __restrict__ xs_bf, const short* __restrict__ WdbcT,
    const float* __restrict__ xs,
    float* __restrict__ dlt, float* __restrict__ u, float* __restrict__ cvv,
    const float* __restrict__ Aa,
    float* __restrict__ tc, float* __restrict__ dsm,
    float* __restrict__ yv,
    const float* __restrict__ szp, const short* __restrict__ W_outT,
    float* __restrict__ out)
{
    cg::grid_group grid = cg::this_grid();

    __shared__ float dls[8][4][LC];            // 8 KB
    __shared__ float scr[8704];                // 34 KB: GEMM tiles / T overlay

    short (*As)[72] = reinterpret_cast<short(*)[72]>(scr);
    short (*Bs)[72] = reinterpret_cast<short(*)[72]>(scr) + 64;
    float (*T)[LC][17] = reinterpret_cast<float(*)[LC][17]>(scr);

    const int t = threadIdx.x, blk = blockIdx.x;

    phase_dbc(blk, t, xs_bf, WdbcT, xs, dlt, u, cvv, As, Bs);
    grid.sync();
    phase_scan1(blk, t, dlt, u, Aa, tc, dsm, dls);
    grid.sync();
    phase_scan2(blk, t, Aa, tc, dsm);
    grid.sync();
    phase_scan3(blk, t, dlt, u, cvv, Aa, tc, yv, dls, T);
    grid.sync();
    phase_out(blk, t, yv, szp, W_outT, out, As, Bs);
}

// ---------------------- standalone fallback kernels -------------------------
__global__ __launch_bounds__(512) void k_dbc_s(
    const short* xs_bf, const short* WdbcT, const float* xs,
    float* dlt, float* u, float* cvv)
{
    __shared__ short As[64][72], Bs[128][72];
    phase_dbc(blockIdx.x, threadIdx.x, xs_bf, WdbcT, xs, dlt, u, cvv, As, Bs);
}

__global__ __launch_bounds__(512) void k_scan1_s(
    const float* dlt, const float* u, const float* Aa, float* tc, float* dsm)
{
    __shared__ float dls[8][4][LC];
    phase_scan1(blockIdx.x, threadIdx.x, dlt, u, Aa, tc, dsm, dls);
}

__global__ __launch_bounds__(512) void k_scan2_s(
    const float* Aa, float* tc, const float* dsm)
{
    phase_scan2(blockIdx.x, threadIdx.x, Aa, tc, dsm);
}

__global__ __launch_bounds__(512) void k_scan3_s(
    const float* dlt, const float* u, const float* cvv, const float* Aa,
    const float* tc, float* yv)
{
    __shared__ float dls[8][4][LC];
    __shared__ float T[8][LC][17];
    phase_scan3(blockIdx.x, threadIdx.x, dlt, u, cvv, Aa, tc, yv, dls, T);
}

__global__ __launch_bounds__(512) void k_out_s(
    const float* yv, const float* szp, const short* W_outT, float* out)
{
    __shared__ short As[64][72], Bs[128][72];
    phase_out(blockIdx.x, threadIdx.x, yv, szp, W_outT, out, As, Bs);
}

// ---------------------------------------------------------------------------
extern "C" void kernel_launch(void* const* d_in, const int* in_sizes, int n_in,
                              void* d_out, int out_size, void* d_ws, size_t ws_size,
                              hipStream_t stream)
{
    const float* x       = (const float*)d_in[0];
    const float* W_in    = (const float*)d_in[1];
    const float* W_delta = (const float*)d_in[2];
    const float* W_B     = (const float*)d_in[3];
    const float* W_C     = (const float*)d_in[4];
    const float* W_out   = (const float*)d_in[5];
    const float* A       = (const float*)d_in[6];

    float* out = (float*)d_out;
    float* ws  = (float*)d_ws;

    const size_t S = (size_t)MROWS * DI;
    float* xs  = ws;
    float* sz  = ws + S;
    float* dlt = ws + 2 * S;
    float* u   = ws + 3 * S;
    float* cv  = ws + 4 * S;
    float* yv  = ws + 5 * S;
    float* tc  = ws + 6 * S;                              // 1024*8*256 = 8 MB
    float* dsm = tc + (size_t)1024 * NC * 256;            // 8192 floats

    short* xs_bf  = (short*)(dsm + (size_t)1024 * NC);
    short* WdbcT  = xs_bf + (size_t)MROWS * DI;
    short* W_outT = WdbcT + (size_t)768 * DI;

    k_proj_mfma<<<dim3(15, 32), 256, 0, stream>>>(x, W_in, W_delta, W_B, W_C, W_out,
                                                  xs, xs_bf, sz, WdbcT, W_outT);

    void* kargs[] = {
        (void*)&xs_bf, (void*)&WdbcT, (void*)&xs,
        (void*)&dlt, (void*)&u, (void*)&cv,
        (void*)&A, (void*)&tc, (void*)&dsm, (void*)&yv,
        (void*)&sz, (void*)&W_outT, (void*)&out
    };
    hipError_t ce = hipLaunchCooperativeKernel((void*)k_fused, dim3(256), dim3(512),
                                               kargs, 0, stream);
    if (ce != hipSuccess) {
        (void)hipGetLastError();   // clear sticky error, fall back to 5 launches
        k_dbc_s  <<<dim3(192), 512, 0, stream>>>(xs_bf, WdbcT, xs, dlt, u, cv);
        k_scan1_s<<<dim3(256), 512, 0, stream>>>(dlt, u, A, tc, dsm);
        k_scan2_s<<<dim3(256), 512, 0, stream>>>(A, tc, dsm);
        k_scan3_s<<<dim3(256), 512, 0, stream>>>(dlt, u, cv, A, tc, yv);
        k_out_s  <<<dim3(32),  512, 0, stream>>>(yv, sz, W_outT, out);
    }
}

// Round 11
// 72.027 us; speedup vs baseline: 2.7123x; 2.7123x over previous
//
#include <hip/hip_runtime.h>
#include <hip/hip_bf16.h>

// Mamba block: B=4, L=512, D_MODEL=128, D_INNER=D_STATE=256
// 5 launches: [proj MFMA + weight-prep] -> dbc MFMA (64x128 tiles) ->
// scan1 (chunk-local) -> scan3 (inline chunk-combine + outputs) -> out MFMA

#define MROWS 2048
#define DM 128
#define DI 256
#define DS 256
#define LLEN 512
#define LC 64
#define NC 8

#define LOG2E 1.44269504088896340736f

typedef short bf16x8 __attribute__((ext_vector_type(8)));
typedef float f32x4  __attribute__((ext_vector_type(4)));

__device__ __forceinline__ short f2bf(float f) {
    union { float f; unsigned u; } v; v.f = f;
    unsigned r = v.u + 0x7FFFu + ((v.u >> 16) & 1u);   // RNE
    return (short)(r >> 16);
}

// Taylor-2 exp(a*dl): |a*dl| <= ~0.04 -> rel err < 1e-5
#define TEXP2(c1, c2, dl) fmaf(fmaf((c2), (dl), (c1)), (dl), 1.f)

// ---------------------------------------------------------------------------
// 32x32 transpose+convert tile (fp32 src -> bf16 dst, dst N-major)
// ---------------------------------------------------------------------------
__device__ __forceinline__ void tconv(float (*tile)[33],
                                      const float* __restrict__ src,
                                      short* __restrict__ dst,
                                      int Ms, int Ns, int ti, int tj, int tid)
{
    const int r = tid >> 5, c = tid & 31;
#pragma unroll
    for (int i = 0; i < 4; ++i)
        tile[r + 8 * i][c] = src[(size_t)(ti * 32 + r + 8 * i) * Ns + tj * 32 + c];
    __syncthreads();
#pragma unroll
    for (int i = 0; i < 4; ++i)
        dst[(size_t)(tj * 32 + r + 8 * i) * Ms + ti * 32 + c] = f2bf(tile[c][r + 8 * i]);
}

// ---------------------------------------------------------------------------
// kernel 1: in_proj (MFMA) + fused weight-prep blocks  (grid 15x32, 256 thr)
// ---------------------------------------------------------------------------
__global__ __launch_bounds__(256) void k_proj_mfma(
    const float* __restrict__ x, const float* __restrict__ W_in,
    const float* __restrict__ Wd, const float* __restrict__ Wb,
    const float* __restrict__ Wc, const float* __restrict__ W_out,
    float* __restrict__ xs, short* __restrict__ xs_bf, float* __restrict__ sz,
    short* __restrict__ WdbcT, short* __restrict__ W_outT)
{
    const int t = threadIdx.x;

    if (blockIdx.x >= 8) {               // ---- prep role: 224 tiles ----
        __shared__ float tile[32][33];
        const int uu = (blockIdx.x - 8) * 32 + blockIdx.y;
        if (uu < 64)       tconv(tile, Wd,    WdbcT,                       256, 256, uu & 7,         uu >> 3,         t);
        else if (uu < 128) tconv(tile, Wb,    WdbcT + (size_t)256 * 256,   256, 256, (uu - 64) & 7,  (uu - 64) >> 3,  t);
        else if (uu < 192) tconv(tile, Wc,    WdbcT + (size_t)512 * 256,   256, 256, (uu - 128) & 7, (uu - 128) >> 3, t);
        else if (uu < 224) tconv(tile, W_out, W_outT,                      256, 128, (uu - 192) & 7, (uu - 192) >> 3, t);
        return;
    }

    // ---- GEMM role ----
    __shared__ short As[64][136];
    __shared__ short Bs[64][136];
    f32x4 acc[4] = {};
    const int w = t >> 6, lane = t & 63;
    const int srow = t >> 2, sseg = t & 3;
    const int frow = lane & 15, fk = (lane >> 4) << 3;
    const int r0 = blockIdx.y * 64, n0 = blockIdx.x * 64;

    {
        const float* ap = x + (size_t)(r0 + srow) * DM + sseg * 32;
        short tmp[32];
#pragma unroll
        for (int j = 0; j < 8; ++j) {
            float4 f = *(const float4*)(ap + j * 4);
            tmp[j * 4 + 0] = f2bf(f.x); tmp[j * 4 + 1] = f2bf(f.y);
            tmp[j * 4 + 2] = f2bf(f.z); tmp[j * 4 + 3] = f2bf(f.w);
        }
#pragma unroll
        for (int m = 0; m < 4; ++m)
            *(bf16x8*)&As[srow][sseg * 32 + m * 8] = *(bf16x8*)&tmp[m * 8];
    }
    {
#pragma unroll
        for (int i = 0; i < 32; i += 2) {
            const int k = sseg * 32 + i;
            float f0 = W_in[(size_t)k * 512 + n0 + srow];
            float f1 = W_in[(size_t)(k + 1) * 512 + n0 + srow];
            unsigned pk = (unsigned short)f2bf(f0) | ((unsigned)(unsigned short)f2bf(f1) << 16);
            *(unsigned*)&Bs[srow][k] = pk;
        }
    }
    __syncthreads();

#pragma unroll
    for (int kk = 0; kk < 128; kk += 32) {
        bf16x8 af = *(const bf16x8*)&As[w * 16 + frow][kk + fk];
#pragma unroll
        for (int ct = 0; ct < 4; ++ct) {
            bf16x8 bfr = *(const bf16x8*)&Bs[ct * 16 + frow][kk + fk];
            acc[ct] = __builtin_amdgcn_mfma_f32_16x16x32_bf16(af, bfr, acc[ct], 0, 0, 0);
        }
    }

    const int rr = r0 + w * 16 + (lane >> 4) * 4;
    const int c0 = n0 + (lane & 15);
#pragma unroll
    for (int ct = 0; ct < 4; ++ct) {
        const int c = c0 + ct * 16;
#pragma unroll
        for (int rg = 0; rg < 4; ++rg) {
            const float v = acc[ct][rg];
            const int r = rr + rg;
            if (c < DI) {
                xs[(size_t)r * DI + c]    = v;
                xs_bf[(size_t)r * DI + c] = f2bf(v);
            } else {
                sz[(size_t)r * DI + (c - DI)] = v / (1.f + __expf(-v));
            }
        }
    }
}

// ---------------------------------------------------------------------------
// kernel 2: dbc GEMM — 192 blocks x 512 thr, tile 64r x 128c, K=256
// (verified in R10's cooperative run)
// ---------------------------------------------------------------------------
__global__ __launch_bounds__(512) void k_dbc(
    const short* __restrict__ xs_bf, const short* __restrict__ WdbcT,
    const float* __restrict__ xs,
    float* __restrict__ dlt, float* __restrict__ u, float* __restrict__ cvv)
{
    __shared__ short As[64][72], Bs[128][72];
    const int blk = blockIdx.x, t = threadIdx.x;
    const int w8 = t >> 6, lane = t & 63;
    const int rf = w8 & 3, ch = w8 >> 2;
    const int frow = lane & 15, fk = (lane >> 4) << 3;
    const int bx = blk % 6, by = blk / 6;
    const int r0 = by * 64, n0 = bx * 128;
    const int arow = t >> 3, ak = (t & 7) * 8;
    const int brow = t >> 2, bk = (t & 3) * 16;
    f32x4 acc[4] = {};

    for (int k0 = 0; k0 < DI; k0 += 64) {
        bf16x8 a0 = *(const bf16x8*)(xs_bf + (size_t)(r0 + arow) * DI + k0 + ak);
        bf16x8 b0 = *(const bf16x8*)(WdbcT + (size_t)(n0 + brow) * DI + k0 + bk);
        bf16x8 b1 = *(const bf16x8*)(WdbcT + (size_t)(n0 + brow) * DI + k0 + bk + 8);
        __syncthreads();
        *(bf16x8*)&As[arow][ak]     = a0;
        *(bf16x8*)&Bs[brow][bk]     = b0;
        *(bf16x8*)&Bs[brow][bk + 8] = b1;
        __syncthreads();
#pragma unroll
        for (int kk = 0; kk < 64; kk += 32) {
            bf16x8 af = *(const bf16x8*)&As[rf * 16 + frow][kk + fk];
#pragma unroll
            for (int ct = 0; ct < 4; ++ct) {
                bf16x8 bfr = *(const bf16x8*)&Bs[(ch * 4 + ct) * 16 + frow][kk + fk];
                acc[ct] = __builtin_amdgcn_mfma_f32_16x16x32_bf16(af, bfr, acc[ct], 0, 0, 0);
            }
        }
    }

    const int rr = r0 + rf * 16 + (lane >> 4) * 4;
    const int nbase = n0 + ch * 64;
    const int wsel = nbase >> 8;          // 0: delta, 1: B, 2: C
    const int nb = nbase & 255;
#pragma unroll
    for (int ct = 0; ct < 4; ++ct) {
        const int c = nb + ct * 16 + (lane & 15);
#pragma unroll
        for (int rg = 0; rg < 4; ++rg) {
            const float v = acc[ct][rg];
            const size_t idx = (size_t)(rr + rg) * DI + c;
            if (wsel == 0)      dlt[idx] = v;
            else if (wsel == 1) u[idx]   = v * xs[idx];   // Bv * xs
            else                cvv[idx] = v;
        }
    }
}

// ---------------------------------------------------------------------------
// kernel 3: scan pass 1 — chunk-local states. 512 blocks x 4 waves.
// ---------------------------------------------------------------------------
__global__ __launch_bounds__(256) void k_scan1(
    const float* __restrict__ dlt, const float* __restrict__ u,
    const float* __restrict__ Aa,
    float* __restrict__ tc, float* __restrict__ dsm)
{
    const int lane = threadIdx.x & 63;
    const int w    = threadIdx.x >> 6;
    const int blk  = blockIdx.x;
    const int b  = blk & 3;
    const int c  = (blk >> 2) & 7;
    const int d0 = ((blk >> 5) * 4 + w) * 4;

    __shared__ float dls[4][4][LC];
    const size_t base = (size_t)b * LLEN * DI + (size_t)c * LC * DI;

    float4 dv = *(const float4*)(dlt + base + (size_t)lane * DI + d0);
    dls[w][0][lane] = dv.x;
    dls[w][1][lane] = dv.y;
    dls[w][2][lane] = dv.z;
    dls[w][3][lane] = dv.w;
    float dsv[4] = { dv.x, dv.y, dv.z, dv.w };
#pragma unroll
    for (int dd = 0; dd < 4; ++dd) {
#pragma unroll
        for (int off = 32; off > 0; off >>= 1)
            dsv[dd] += __shfl_xor(dsv[dd], off);
    }

    float4 c1[4], c2[4];
#pragma unroll
    for (int dd = 0; dd < 4; ++dd) {
        float4 a = *(const float4*)(Aa + (size_t)(d0 + dd) * DS + lane * 4);
        c1[dd] = a;
        c2[dd] = make_float4(0.5f * a.x * a.x, 0.5f * a.y * a.y,
                             0.5f * a.z * a.z, 0.5f * a.w * a.w);
    }

    const float4* up = (const float4*)(u + base) + lane;
    float4 s[4] = {};

    for (int g = 0; g < LC / 4; ++g) {
        float4 uv[4];
#pragma unroll
        for (int i = 0; i < 4; ++i)
            uv[i] = up[(size_t)(g * 4 + i) * 64];
#pragma unroll
        for (int i = 0; i < 4; ++i) {
            const int l = g * 4 + i;
#pragma unroll
            for (int dd = 0; dd < 4; ++dd) {
                const float dl = dls[w][dd][l];
                s[dd].x = fmaf(TEXP2(c1[dd].x, c2[dd].x, dl), s[dd].x, dl * uv[i].x);
                s[dd].y = fmaf(TEXP2(c1[dd].y, c2[dd].y, dl), s[dd].y, dl * uv[i].y);
                s[dd].z = fmaf(TEXP2(c1[dd].z, c2[dd].z, dl), s[dd].z, dl * uv[i].z);
                s[dd].w = fmaf(TEXP2(c1[dd].w, c2[dd].w, dl), s[dd].w, dl * uv[i].w);
            }
        }
    }

    const size_t rbb = ((size_t)(b * 256 + d0)) * NC + c;
#pragma unroll
    for (int dd = 0; dd < 4; ++dd) {
        *(float4*)(tc + (rbb + (size_t)dd * NC) * 256 + lane * 4) = s[dd];
        if (lane == 0) dsm[rbb + dd * NC] = dsv[dd];
    }
}

// ---------------------------------------------------------------------------
// kernel 4: scan pass 3 — inline chunk-combine prologue + outputs.
// s_init[c] = sum_{cc<c} (prod_{cc<j<c} e(Dsum_j)) T_cc computed per wave
// (avg 3.5 combines x 4d x 4 comp exp2 ~ trivial); tc read-only.
// ---------------------------------------------------------------------------
__global__ __launch_bounds__(256) void k_scan3(
    const float* __restrict__ dlt, const float* __restrict__ u,
    const float* __restrict__ cvv, const float* __restrict__ Aa,
    const float* __restrict__ tc, const float* __restrict__ dsm,
    float* __restrict__ yv)
{
    const int lane = threadIdx.x & 63;
    const int w    = threadIdx.x >> 6;
    const int blk  = blockIdx.x;
    const int b  = blk & 3;
    const int c  = (blk >> 2) & 7;
    const int d0 = ((blk >> 5) * 4 + w) * 4;

    __shared__ float dls[4][4][LC];
    __shared__ float T[4][LC][17];

    const size_t base = (size_t)b * LLEN * DI + (size_t)c * LC * DI;

    float4 dv = *(const float4*)(dlt + base + (size_t)lane * DI + d0);
    dls[w][0][lane] = dv.x;
    dls[w][1][lane] = dv.y;
    dls[w][2][lane] = dv.z;
    dls[w][3][lane] = dv.w;

    float4 c1[4], c2[4];
#pragma unroll
    for (int dd = 0; dd < 4; ++dd) {
        float4 a = *(const float4*)(Aa + (size_t)(d0 + dd) * DS + lane * 4);
        c1[dd] = a;
        c2[dd] = make_float4(0.5f * a.x * a.x, 0.5f * a.y * a.y,
                             0.5f * a.z * a.z, 0.5f * a.w * a.w);
    }

    // ---- inline combine: s = s_init[c] from chunks 0..c-1 ----
    float4 s[4] = {};
    for (int cc = 0; cc < c; ++cc) {
#pragma unroll
        for (int dd = 0; dd < 4; ++dd) {
            const size_t rbd = ((size_t)(b * 256 + d0 + dd)) * NC + cc;
            const float4 Tt = *(const float4*)(tc + rbd * 256 + lane * 4);
            const float  Dc = dsm[rbd] * LOG2E;
            s[dd].x = exp2f(c1[dd].x * Dc) * s[dd].x + Tt.x;
            s[dd].y = exp2f(c1[dd].y * Dc) * s[dd].y + Tt.y;
            s[dd].z = exp2f(c1[dd].z * Dc) * s[dd].z + Tt.z;
            s[dd].w = exp2f(c1[dd].w * Dc) * s[dd].w + Tt.w;
        }
    }

    const float4* up = (const float4*)(u + base) + lane;
    const float4* cp = (const float4*)(cvv + base) + lane;
    float* yb = yv + base;

    const int col = lane & 15, seg = lane >> 4;

    for (int g = 0; g < LC / 4; ++g) {
        float4 uv[4], cV[4];
#pragma unroll
        for (int i = 0; i < 4; ++i) {
            uv[i] = up[(size_t)(g * 4 + i) * 64];
            cV[i] = cp[(size_t)(g * 4 + i) * 64];
        }
#pragma unroll
        for (int i = 0; i < 4; ++i) {
            const int l = g * 4 + i;
#pragma unroll
            for (int dd = 0; dd < 4; ++dd) {
                const float dl = dls[w][dd][l];
                s[dd].x = fmaf(TEXP2(c1[dd].x, c2[dd].x, dl), s[dd].x, dl * uv[i].x);
                s[dd].y = fmaf(TEXP2(c1[dd].y, c2[dd].y, dl), s[dd].y, dl * uv[i].y);
                s[dd].z = fmaf(TEXP2(c1[dd].z, c2[dd].z, dl), s[dd].z, dl * uv[i].z);
                s[dd].w = fmaf(TEXP2(c1[dd].w, c2[dd].w, dl), s[dd].w, dl * uv[i].w);
                T[w][lane][dd * 4 + i] =
                    fmaf(s[dd].w, cV[i].w, fmaf(s[dd].z, cV[i].z,
                         fmaf(s[dd].y, cV[i].y, s[dd].x * cV[i].x)));
            }
        }
        // flush 4 steps: 16 cols x 64 rows; 4 lanes per column
        float sm = 0.f;
#pragma unroll
        for (int r = 0; r < 16; ++r)
            sm += T[w][seg * 16 + r][col];
        sm += __shfl_xor(sm, 16);
        sm += __shfl_xor(sm, 32);
        if (lane < 16)
            yb[(size_t)(g * 4 + (col & 3)) * DI + d0 + (col >> 2)] = sm;
    }
}

// ---------------------------------------------------------------------------
// kernel 5: out GEMM (MFMA) — 64 blocks x 256 thr
// ---------------------------------------------------------------------------
__global__ __launch_bounds__(256) void k_out_mfma(
    const float* __restrict__ y, const float* __restrict__ szp,
    const short* __restrict__ W_outT, float* __restrict__ out)
{
    __shared__ short As[64][72], Bs[64][72];
    f32x4 acc[4] = {};
    const int tid  = threadIdx.x;
    const int w    = tid >> 6, lane = tid & 63;
    const int srow = tid >> 2, sseg = tid & 3;
    const int frow = lane & 15, fk = (lane >> 4) << 3;
    const int r0 = blockIdx.y * 64, n0 = blockIdx.x * 64;

    for (int k0 = 0; k0 < DI; k0 += 64) {
        const size_t aoff = (size_t)(r0 + srow) * DI + k0 + sseg * 16;
        float4 y0 = *(const float4*)(y + aoff);
        float4 y1 = *(const float4*)(y + aoff + 4);
        float4 y2 = *(const float4*)(y + aoff + 8);
        float4 y3 = *(const float4*)(y + aoff + 12);
        float4 s0 = *(const float4*)(szp + aoff);
        float4 s1 = *(const float4*)(szp + aoff + 4);
        float4 s2 = *(const float4*)(szp + aoff + 8);
        float4 s3 = *(const float4*)(szp + aoff + 12);
        const short* bg = W_outT + (size_t)(n0 + srow) * DI + k0 + sseg * 16;
        bf16x8 b0 = *(const bf16x8*)bg;
        bf16x8 b1 = *(const bf16x8*)(bg + 8);
        bf16x8 a0, a1;
        a0[0] = f2bf(y0.x * s0.x); a0[1] = f2bf(y0.y * s0.y);
        a0[2] = f2bf(y0.z * s0.z); a0[3] = f2bf(y0.w * s0.w);
        a0[4] = f2bf(y1.x * s1.x); a0[5] = f2bf(y1.y * s1.y);
        a0[6] = f2bf(y1.z * s1.z); a0[7] = f2bf(y1.w * s1.w);
        a1[0] = f2bf(y2.x * s2.x); a1[1] = f2bf(y2.y * s2.y);
        a1[2] = f2bf(y2.z * s2.z); a1[3] = f2bf(y2.w * s2.w);
        a1[4] = f2bf(y3.x * s3.x); a1[5] = f2bf(y3.y * s3.y);
        a1[6] = f2bf(y3.z * s3.z); a1[7] = f2bf(y3.w * s3.w);
        __syncthreads();
        *(bf16x8*)&As[srow][sseg * 16]     = a0;
        *(bf16x8*)&As[srow][sseg * 16 + 8] = a1;
        *(bf16x8*)&Bs[srow][sseg * 16]     = b0;
        *(bf16x8*)&Bs[srow][sseg * 16 + 8] = b1;
        __syncthreads();
#pragma unroll
        for (int kk = 0; kk < 64; kk += 32) {
            bf16x8 af = *(const bf16x8*)&As[w * 16 + frow][kk + fk];
#pragma unroll
            for (int ct = 0; ct < 4; ++ct) {
                bf16x8 bfr = *(const bf16x8*)&Bs[ct * 16 + frow][kk + fk];
                acc[ct] = __builtin_amdgcn_mfma_f32_16x16x32_bf16(af, bfr, acc[ct], 0, 0, 0);
            }
        }
    }

    const int rr = r0 + w * 16 + (lane >> 4) * 4;
    const int c0 = n0 + (lane & 15);
#pragma unroll
    for (int ct = 0; ct < 4; ++ct) {
        const int c = c0 + ct * 16;
#pragma unroll
        for (int rg = 0; rg < 4; ++rg)
            out[(size_t)(rr + rg) * DM + c] = acc[ct][rg];
    }
}

// ---------------------------------------------------------------------------
extern "C" void kernel_launch(void* const* d_in, const int* in_sizes, int n_in,
                              void* d_out, int out_size, void* d_ws, size_t ws_size,
                              hipStream_t stream)
{
    const float* x       = (const float*)d_in[0];
    const float* W_in    = (const float*)d_in[1];
    const float* W_delta = (const float*)d_in[2];
    const float* W_B     = (const float*)d_in[3];
    const float* W_C     = (const float*)d_in[4];
    const float* W_out   = (const float*)d_in[5];
    const float* A       = (const float*)d_in[6];
    // d_in[7] = D, unused by the reference scan

    float* out = (float*)d_out;
    float* ws  = (float*)d_ws;

    const size_t S = (size_t)MROWS * DI;   // 524288 floats per plane (2 MB)
    float* xs  = ws;
    float* sz  = ws + S;
    float* dlt = ws + 2 * S;
    float* u   = ws + 3 * S;
    float* cv  = ws + 4 * S;
    float* yv  = ws + 5 * S;
    float* tc  = ws + 6 * S;                              // 1024*8*256 = 8 MB
    float* dsm = tc + (size_t)1024 * NC * 256;            // 8192 floats

    short* xs_bf  = (short*)(dsm + (size_t)1024 * NC);    // 2048*256
    short* WdbcT  = xs_bf + (size_t)MROWS * DI;           // 768*256
    short* W_outT = WdbcT + (size_t)768 * DI;             // 128*256

    k_proj_mfma<<<dim3(15, 32), 256, 0, stream>>>(x, W_in, W_delta, W_B, W_C, W_out,
                                                  xs, xs_bf, sz, WdbcT, W_outT);
    k_dbc      <<<dim3(192), 512, 0, stream>>>(xs_bf, WdbcT, xs, dlt, u, cv);
    k_scan1    <<<dim3(512), 256, 0, stream>>>(dlt, u, A, tc, dsm);
    k_scan3    <<<dim3(512), 256, 0, stream>>>(dlt, u, cv, A, tc, dsm, yv);
    k_out_mfma <<<dim3(2, 32), 256, 0, stream>>>(yv, sz, W_outT, out);
}

// Round 13
// 69.561 us; speedup vs baseline: 2.8085x; 1.0355x over previous
//
#include <hip/hip_runtime.h>
#include <hip/hip_bf16.h>

// Mamba block: B=4, L=512, D_MODEL=128, D_INNER=D_STATE=256
// 5 launches: [proj MFMA + weight-prep] -> dbc MFMA (64x128 tiles) ->
// scan1 (chunk-local, dbuf prefetch) -> scan3 (inline combine + outputs,
// dbuf prefetch, vectorized T writes) -> out MFMA

#define MROWS 2048
#define DM 128
#define DI 256
#define DS 256
#define LLEN 512
#define LC 64
#define NC 8

#define LOG2E 1.44269504088896340736f

typedef short bf16x8 __attribute__((ext_vector_type(8)));
typedef float f32x4  __attribute__((ext_vector_type(4)));

__device__ __forceinline__ short f2bf(float f) {
    union { float f; unsigned u; } v; v.f = f;
    unsigned r = v.u + 0x7FFFu + ((v.u >> 16) & 1u);   // RNE
    return (short)(r >> 16);
}

// Taylor-2 exp(a*dl): |a*dl| <= ~0.04 -> rel err < 1e-5
#define TEXP2(c1, c2, dl) fmaf(fmaf((c2), (dl), (c1)), (dl), 1.f)

// ---------------------------------------------------------------------------
// 32x32 transpose+convert tile (fp32 src -> bf16 dst, dst N-major)
// ---------------------------------------------------------------------------
__device__ __forceinline__ void tconv(float (*tile)[33],
                                      const float* __restrict__ src,
                                      short* __restrict__ dst,
                                      int Ms, int Ns, int ti, int tj, int tid)
{
    const int r = tid >> 5, c = tid & 31;
#pragma unroll
    for (int i = 0; i < 4; ++i)
        tile[r + 8 * i][c] = src[(size_t)(ti * 32 + r + 8 * i) * Ns + tj * 32 + c];
    __syncthreads();
#pragma unroll
    for (int i = 0; i < 4; ++i)
        dst[(size_t)(tj * 32 + r + 8 * i) * Ms + ti * 32 + c] = f2bf(tile[c][r + 8 * i]);
}

// ---------------------------------------------------------------------------
// kernel 1: in_proj (MFMA) + fused weight-prep blocks  (grid 15x32, 256 thr)
// ---------------------------------------------------------------------------
__global__ __launch_bounds__(256) void k_proj_mfma(
    const float* __restrict__ x, const float* __restrict__ W_in,
    const float* __restrict__ Wd, const float* __restrict__ Wb,
    const float* __restrict__ Wc, const float* __restrict__ W_out,
    float* __restrict__ xs, short* __restrict__ xs_bf, float* __restrict__ sz,
    short* __restrict__ WdbcT, short* __restrict__ W_outT)
{
    const int t = threadIdx.x;

    if (blockIdx.x >= 8) {               // ---- prep role: 224 tiles ----
        __shared__ float tile[32][33];
        const int uu = (blockIdx.x - 8) * 32 + blockIdx.y;
        if (uu < 64)       tconv(tile, Wd,    WdbcT,                       256, 256, uu & 7,         uu >> 3,         t);
        else if (uu < 128) tconv(tile, Wb,    WdbcT + (size_t)256 * 256,   256, 256, (uu - 64) & 7,  (uu - 64) >> 3,  t);
        else if (uu < 192) tconv(tile, Wc,    WdbcT + (size_t)512 * 256,   256, 256, (uu - 128) & 7, (uu - 128) >> 3, t);
        else if (uu < 224) tconv(tile, W_out, W_outT,                      256, 128, (uu - 192) & 7, (uu - 192) >> 3, t);
        return;
    }

    // ---- GEMM role ----
    __shared__ short As[64][136];
    __shared__ short Bs[64][136];
    f32x4 acc[4] = {};
    const int w = t >> 6, lane = t & 63;
    const int srow = t >> 2, sseg = t & 3;
    const int frow = lane & 15, fk = (lane >> 4) << 3;
    const int r0 = blockIdx.y * 64, n0 = blockIdx.x * 64;

    {
        const float* ap = x + (size_t)(r0 + srow) * DM + sseg * 32;
        short tmp[32];
#pragma unroll
        for (int j = 0; j < 8; ++j) {
            float4 f = *(const float4*)(ap + j * 4);
            tmp[j * 4 + 0] = f2bf(f.x); tmp[j * 4 + 1] = f2bf(f.y);
            tmp[j * 4 + 2] = f2bf(f.z); tmp[j * 4 + 3] = f2bf(f.w);
        }
#pragma unroll
        for (int m = 0; m < 4; ++m)
            *(bf16x8*)&As[srow][sseg * 32 + m * 8] = *(bf16x8*)&tmp[m * 8];
    }
    {
#pragma unroll
        for (int i = 0; i < 32; i += 2) {
            const int k = sseg * 32 + i;
            float f0 = W_in[(size_t)k * 512 + n0 + srow];
            float f1 = W_in[(size_t)(k + 1) * 512 + n0 + srow];
            unsigned pk = (unsigned short)f2bf(f0) | ((unsigned)(unsigned short)f2bf(f1) << 16);
            *(unsigned*)&Bs[srow][k] = pk;
        }
    }
    __syncthreads();

#pragma unroll
    for (int kk = 0; kk < 128; kk += 32) {
        bf16x8 af = *(const bf16x8*)&As[w * 16 + frow][kk + fk];
#pragma unroll
        for (int ct = 0; ct < 4; ++ct) {
            bf16x8 bfr = *(const bf16x8*)&Bs[ct * 16 + frow][kk + fk];
            acc[ct] = __builtin_amdgcn_mfma_f32_16x16x32_bf16(af, bfr, acc[ct], 0, 0, 0);
        }
    }

    const int rr = r0 + w * 16 + (lane >> 4) * 4;
    const int c0 = n0 + (lane & 15);
#pragma unroll
    for (int ct = 0; ct < 4; ++ct) {
        const int c = c0 + ct * 16;
#pragma unroll
        for (int rg = 0; rg < 4; ++rg) {
            const float v = acc[ct][rg];
            const int r = rr + rg;
            if (c < DI) {
                xs[(size_t)r * DI + c]    = v;
                xs_bf[(size_t)r * DI + c] = f2bf(v);
            } else {
                sz[(size_t)r * DI + (c - DI)] = v / (1.f + __expf(-v));
            }
        }
    }
}

// ---------------------------------------------------------------------------
// kernel 2: dbc GEMM — 192 blocks x 512 thr, tile 64r x 128c, K=256
// ---------------------------------------------------------------------------
__global__ __launch_bounds__(512) void k_dbc(
    const short* __restrict__ xs_bf, const short* __restrict__ WdbcT,
    const float* __restrict__ xs,
    float* __restrict__ dlt, float* __restrict__ u, float* __restrict__ cvv)
{
    __shared__ short As[64][72], Bs[128][72];
    const int blk = blockIdx.x, t = threadIdx.x;
    const int w8 = t >> 6, lane = t & 63;
    const int rf = w8 & 3, ch = w8 >> 2;
    const int frow = lane & 15, fk = (lane >> 4) << 3;
    const int bx = blk % 6, by = blk / 6;
    const int r0 = by * 64, n0 = bx * 128;
    const int arow = t >> 3, ak = (t & 7) * 8;
    const int brow = t >> 2, bk = (t & 3) * 16;
    f32x4 acc[4] = {};

    for (int k0 = 0; k0 < DI; k0 += 64) {
        bf16x8 a0 = *(const bf16x8*)(xs_bf + (size_t)(r0 + arow) * DI + k0 + ak);
        bf16x8 b0 = *(const bf16x8*)(WdbcT + (size_t)(n0 + brow) * DI + k0 + bk);
        bf16x8 b1 = *(const bf16x8*)(WdbcT + (size_t)(n0 + brow) * DI + k0 + bk + 8);
        __syncthreads();
        *(bf16x8*)&As[arow][ak]     = a0;
        *(bf16x8*)&Bs[brow][bk]     = b0;
        *(bf16x8*)&Bs[brow][bk + 8] = b1;
        __syncthreads();
#pragma unroll
        for (int kk = 0; kk < 64; kk += 32) {
            bf16x8 af = *(const bf16x8*)&As[rf * 16 + frow][kk + fk];
#pragma unroll
            for (int ct = 0; ct < 4; ++ct) {
                bf16x8 bfr = *(const bf16x8*)&Bs[(ch * 4 + ct) * 16 + frow][kk + fk];
                acc[ct] = __builtin_amdgcn_mfma_f32_16x16x32_bf16(af, bfr, acc[ct], 0, 0, 0);
            }
        }
    }

    const int rr = r0 + rf * 16 + (lane >> 4) * 4;
    const int nbase = n0 + ch * 64;
    const int wsel = nbase >> 8;          // 0: delta, 1: B, 2: C
    const int nb = nbase & 255;
#pragma unroll
    for (int ct = 0; ct < 4; ++ct) {
        const int c = nb + ct * 16 + (lane & 15);
#pragma unroll
        for (int rg = 0; rg < 4; ++rg) {
            const float v = acc[ct][rg];
            const size_t idx = (size_t)(rr + rg) * DI + c;
            if (wsel == 0)      dlt[idx] = v;
            else if (wsel == 1) u[idx]   = v * xs[idx];   // Bv * xs
            else                cvv[idx] = v;
        }
    }
}

// ---------------------------------------------------------------------------
// kernel 3: scan pass 1 — chunk-local states, 2-deep register dbuf prefetch.
// ---------------------------------------------------------------------------
__global__ __launch_bounds__(256) void k_scan1(
    const float* __restrict__ dlt, const float* __restrict__ u,
    const float* __restrict__ Aa,
    float* __restrict__ tc, float* __restrict__ dsm)
{
    const int lane = threadIdx.x & 63;
    const int w    = threadIdx.x >> 6;
    const int blk  = blockIdx.x;
    const int b  = blk & 3;
    const int c  = (blk >> 2) & 7;
    const int d0 = ((blk >> 5) * 4 + w) * 4;

    __shared__ float dls[4][4][LC];
    const size_t base = (size_t)b * LLEN * DI + (size_t)c * LC * DI;

    float4 dv = *(const float4*)(dlt + base + (size_t)lane * DI + d0);
    dls[w][0][lane] = dv.x;
    dls[w][1][lane] = dv.y;
    dls[w][2][lane] = dv.z;
    dls[w][3][lane] = dv.w;
    float dsv[4] = { dv.x, dv.y, dv.z, dv.w };
#pragma unroll
    for (int dd = 0; dd < 4; ++dd) {
#pragma unroll
        for (int off = 32; off > 0; off >>= 1)
            dsv[dd] += __shfl_xor(dsv[dd], off);
    }

    float4 c1[4], c2[4];
#pragma unroll
    for (int dd = 0; dd < 4; ++dd) {
        float4 a = *(const float4*)(Aa + (size_t)(d0 + dd) * DS + lane * 4);
        c1[dd] = a;
        c2[dd] = make_float4(0.5f * a.x * a.x, 0.5f * a.y * a.y,
                             0.5f * a.z * a.z, 0.5f * a.w * a.w);
    }

    const float4* up = (const float4*)(u + base) + lane;
    float4 s[4] = {};
    float4 uA[4], uB[4];

#define S1_PRE(UB, G)                                                         \
    {                                                                         \
        _Pragma("unroll")                                                     \
        for (int i = 0; i < 4; ++i)                                           \
            UB[i] = up[(size_t)((G) * 4 + i) * 64];                           \
    }

#define S1_COMP(UB, G)                                                        \
    {                                                                         \
        _Pragma("unroll")                                                     \
        for (int i = 0; i < 4; ++i) {                                         \
            const int l = (G) * 4 + i;                                        \
            _Pragma("unroll")                                                 \
            for (int dd = 0; dd < 4; ++dd) {                                  \
                const float dl = dls[w][dd][l];                               \
                s[dd].x = fmaf(TEXP2(c1[dd].x, c2[dd].x, dl), s[dd].x, dl * UB[i].x); \
                s[dd].y = fmaf(TEXP2(c1[dd].y, c2[dd].y, dl), s[dd].y, dl * UB[i].y); \
                s[dd].z = fmaf(TEXP2(c1[dd].z, c2[dd].z, dl), s[dd].z, dl * UB[i].z); \
                s[dd].w = fmaf(TEXP2(c1[dd].w, c2[dd].w, dl), s[dd].w, dl * UB[i].w); \
            }                                                                 \
        }                                                                     \
    }

    S1_PRE(uA, 0)
    for (int g2 = 0; g2 < 8; ++g2) {
        S1_PRE(uB, g2 * 2 + 1)
        S1_COMP(uA, g2 * 2)
        if (g2 < 7) S1_PRE(uA, g2 * 2 + 2)
        S1_COMP(uB, g2 * 2 + 1)
    }
#undef S1_PRE
#undef S1_COMP

    const size_t rbb = ((size_t)(b * 256 + d0)) * NC + c;
#pragma unroll
    for (int dd = 0; dd < 4; ++dd) {
        *(float4*)(tc + (rbb + (size_t)dd * NC) * 256 + lane * 4) = s[dd];
        if (lane == 0) dsm[rbb + dd * NC] = dsv[dd];
    }
}

// ---------------------------------------------------------------------------
// kernel 4: scan pass 3 — inline chunk-combine prologue + outputs.
// 2-deep register dbuf prefetch; per-group float4 T writes (stride 20 ->
// 16B-aligned rows, conflict-free b128); flush every 4 steps.
// ---------------------------------------------------------------------------
__global__ __launch_bounds__(256) void k_scan3(
    const float* __restrict__ dlt, const float* __restrict__ u,
    const float* __restrict__ cvv, const float* __restrict__ Aa,
    const float* __restrict__ tc, const float* __restrict__ dsm,
    float* __restrict__ yv)
{
    const int lane = threadIdx.x & 63;
    const int w    = threadIdx.x >> 6;
    const int blk  = blockIdx.x;
    const int b  = blk & 3;
    const int c  = (blk >> 2) & 7;
    const int d0 = ((blk >> 5) * 4 + w) * 4;

    __shared__ float dls[4][4][LC];
    __shared__ float T[4][LC][20];      // stride 20 floats = 80B (16B aligned)

    const size_t base = (size_t)b * LLEN * DI + (size_t)c * LC * DI;

    float4 dv = *(const float4*)(dlt + base + (size_t)lane * DI + d0);
    dls[w][0][lane] = dv.x;
    dls[w][1][lane] = dv.y;
    dls[w][2][lane] = dv.z;
    dls[w][3][lane] = dv.w;

    float4 c1[4], c2[4];
#pragma unroll
    for (int dd = 0; dd < 4; ++dd) {
        float4 a = *(const float4*)(Aa + (size_t)(d0 + dd) * DS + lane * 4);
        c1[dd] = a;
        c2[dd] = make_float4(0.5f * a.x * a.x, 0.5f * a.y * a.y,
                             0.5f * a.z * a.z, 0.5f * a.w * a.w);
    }

    // ---- inline combine: s = s_init[c] from chunks 0..c-1 ----
    float4 s[4] = {};
    for (int cc = 0; cc < c; ++cc) {
#pragma unroll
        for (int dd = 0; dd < 4; ++dd) {
            const size_t rbd = ((size_t)(b * 256 + d0 + dd)) * NC + cc;
            const float4 Tt = *(const float4*)(tc + rbd * 256 + lane * 4);
            const float  Dc = dsm[rbd] * LOG2E;
            s[dd].x = exp2f(c1[dd].x * Dc) * s[dd].x + Tt.x;
            s[dd].y = exp2f(c1[dd].y * Dc) * s[dd].y + Tt.y;
            s[dd].z = exp2f(c1[dd].z * Dc) * s[dd].z + Tt.z;
            s[dd].w = exp2f(c1[dd].w * Dc) * s[dd].w + Tt.w;
        }
    }

    const float4* up = (const float4*)(u + base) + lane;
    const float4* cp = (const float4*)(cvv + base) + lane;
    float* yb = yv + base;

    const int col = lane & 15, seg = lane >> 4;
    float4 uA[4], cA[4], uB[4], cB[4];

#define S3_PRE(UB, CB, G)                                                     \
    {                                                                         \
        _Pragma("unroll")                                                     \
        for (int i = 0; i < 4; ++i) {                                         \
            UB[i] = up[(size_t)((G) * 4 + i) * 64];                           \
            CB[i] = cp[(size_t)((G) * 4 + i) * 64];                           \
        }                                                                     \
    }

#define S3_COMP(UB, CB, G)                                                    \
    {                                                                         \
        f32x4 pacc[4];                                                        \
        _Pragma("unroll")                                                     \
        for (int i = 0; i < 4; ++i) {                                         \
            const int l = (G) * 4 + i;                                        \
            _Pragma("unroll")                                                 \
            for (int dd = 0; dd < 4; ++dd) {                                  \
                const float dl = dls[w][dd][l];                               \
                s[dd].x = fmaf(TEXP2(c1[dd].x, c2[dd].x, dl), s[dd].x, dl * UB[i].x); \
                s[dd].y = fmaf(TEXP2(c1[dd].y, c2[dd].y, dl), s[dd].y, dl * UB[i].y); \
                s[dd].z = fmaf(TEXP2(c1[dd].z, c2[dd].z, dl), s[dd].z, dl * UB[i].z); \
                s[dd].w = fmaf(TEXP2(c1[dd].w, c2[dd].w, dl), s[dd].w, dl * UB[i].w); \
                pacc[dd][i] =                                                 \
                    fmaf(s[dd].w, CB[i].w, fmaf(s[dd].z, CB[i].z,             \
                         fmaf(s[dd].y, CB[i].y, s[dd].x * CB[i].x)));         \
            }                                                                 \
        }                                                                     \
        _Pragma("unroll")                                                     \
        for (int dd = 0; dd < 4; ++dd)                                        \
            *(f32x4*)&T[w][lane][dd * 4] = pacc[dd];                          \
        float sm = 0.f;                                                       \
        _Pragma("unroll")                                                     \
        for (int r = 0; r < 16; ++r)                                          \
            sm += T[w][seg * 16 + r][col];                                    \
        sm += __shfl_xor(sm, 16);                                             \
        sm += __shfl_xor(sm, 32);                                             \
        if (lane < 16)                                                        \
            yb[(size_t)((G) * 4 + (col & 3)) * DI + d0 + (col >> 2)] = sm;    \
    }

    S3_PRE(uA, cA, 0)
    for (int g2 = 0; g2 < 8; ++g2) {
        S3_PRE(uB, cB, g2 * 2 + 1)
        S3_COMP(uA, cA, g2 * 2)
        if (g2 < 7) S3_PRE(uA, cA, g2 * 2 + 2)
        S3_COMP(uB, cB, g2 * 2 + 1)
    }
#undef S3_PRE
#undef S3_COMP
}

// ---------------------------------------------------------------------------
// kernel 5: out GEMM (MFMA) — 64 blocks x 256 thr
// ---------------------------------------------------------------------------
__global__ __launch_bounds__(256) void k_out_mfma(
    const float* __restrict__ y, const float* __restrict__ szp,
    const short* __restrict__ W_outT, float* __restrict__ out)
{
    __shared__ short As[64][72], Bs[64][72];
    f32x4 acc[4] = {};
    const int tid  = threadIdx.x;
    const int w    = tid >> 6, lane = tid & 63;
    const int srow = tid >> 2, sseg = tid & 3;
    const int frow = lane & 15, fk = (lane >> 4) << 3;
    const int r0 = blockIdx.y * 64, n0 = blockIdx.x * 64;

    for (int k0 = 0; k0 < DI; k0 += 64) {
        const size_t aoff = (size_t)(r0 + srow) * DI + k0 + sseg * 16;
        float4 y0 = *(const float4*)(y + aoff);
        float4 y1 = *(const float4*)(y + aoff + 4);
        float4 y2 = *(const float4*)(y + aoff + 8);
        float4 y3 = *(const float4*)(y + aoff + 12);
        float4 s0 = *(const float4*)(szp + aoff);
        float4 s1 = *(const float4*)(szp + aoff + 4);
        float4 s2 = *(const float4*)(szp + aoff + 8);
        float4 s3 = *(const float4*)(szp + aoff + 12);
        const short* bg = W_outT + (size_t)(n0 + srow) * DI + k0 + sseg * 16;
        bf16x8 b0 = *(const bf16x8*)bg;
        bf16x8 b1 = *(const bf16x8*)(bg + 8);
        bf16x8 a0, a1;
        a0[0] = f2bf(y0.x * s0.x); a0[1] = f2bf(y0.y * s0.y);
        a0[2] = f2bf(y0.z * s0.z); a0[3] = f2bf(y0.w * s0.w);
        a0[4] = f2bf(y1.x * s1.x); a0[5] = f2bf(y1.y * s1.y);
        a0[6] = f2bf(y1.z * s1.z); a0[7] = f2bf(y1.w * s1.w);
        a1[0] = f2bf(y2.x * s2.x); a1[1] = f2bf(y2.y * s2.y);
        a1[2] = f2bf(y2.z * s2.z); a1[3] = f2bf(y2.w * s2.w);
        a1[4] = f2bf(y3.x * s3.x); a1[5] = f2bf(y3.y * s3.y);
        a1[6] = f2bf(y3.z * s3.z); a1[7] = f2bf(y3.w * s3.w);
        __syncthreads();
        *(bf16x8*)&As[srow][sseg * 16]     = a0;
        *(bf16x8*)&As[srow][sseg * 16 + 8] = a1;
        *(bf16x8*)&Bs[srow][sseg * 16]     = b0;
        *(bf16x8*)&Bs[srow][sseg * 16 + 8] = b1;
        __syncthreads();
#pragma unroll
        for (int kk = 0; kk < 64; kk += 32) {
            bf16x8 af = *(const bf16x8*)&As[w * 16 + frow][kk + fk];
#pragma unroll
            for (int ct = 0; ct < 4; ++ct) {
                bf16x8 bfr = *(const bf16x8*)&Bs[ct * 16 + frow][kk + fk];
                acc[ct] = __builtin_amdgcn_mfma_f32_16x16x32_bf16(af, bfr, acc[ct], 0, 0, 0);
            }
        }
    }

    const int rr = r0 + w * 16 + (lane >> 4) * 4;
    const int c0 = n0 + (lane & 15);
#pragma unroll
    for (int ct = 0; ct < 4; ++ct) {
        const int c = c0 + ct * 16;
#pragma unroll
        for (int rg = 0; rg < 4; ++rg)
            out[(size_t)(rr + rg) * DM + c] = acc[ct][rg];
    }
}

// ---------------------------------------------------------------------------
extern "C" void kernel_launch(void* const* d_in, const int* in_sizes, int n_in,
                              void* d_out, int out_size, void* d_ws, size_t ws_size,
                              hipStream_t stream)
{
    const float* x       = (const float*)d_in[0];
    const float* W_in    = (const float*)d_in[1];
    const float* W_delta = (const float*)d_in[2];
    const float* W_B     = (const float*)d_in[3];
    const float* W_C     = (const float*)d_in[4];
    const float* W_out   = (const float*)d_in[5];
    const float* A       = (const float*)d_in[6];
    // d_in[7] = D, unused by the reference scan

    float* out = (float*)d_out;
    float* ws  = (float*)d_ws;

    const size_t S = (size_t)MROWS * DI;   // 524288 floats per plane (2 MB)
    float* xs  = ws;
    float* sz  = ws + S;
    float* dlt = ws + 2 * S;
    float* u   = ws + 3 * S;
    float* cv  = ws + 4 * S;
    float* yv  = ws + 5 * S;
    float* tc  = ws + 6 * S;                              // 1024*8*256 = 8 MB
    float* dsm = tc + (size_t)1024 * NC * 256;            // 8192 floats

    short* xs_bf  = (short*)(dsm + (size_t)1024 * NC);    // 2048*256
    short* WdbcT  = xs_bf + (size_t)MROWS * DI;           // 768*256
    short* W_outT = WdbcT + (size_t)768 * DI;             // 128*256

    k_proj_mfma<<<dim3(15, 32), 256, 0, stream>>>(x, W_in, W_delta, W_B, W_C, W_out,
                                                  xs, xs_bf, sz, WdbcT, W_outT);
    k_dbc      <<<dim3(192), 512, 0, stream>>>(xs_bf, WdbcT, xs, dlt, u, cv);
    k_scan1    <<<dim3(512), 256, 0, stream>>>(dlt, u, A, tc, dsm);
    k_scan3    <<<dim3(512), 256, 0, stream>>>(dlt, u, cv, A, tc, dsm, yv);
    k_out_mfma <<<dim3(2, 32), 256, 0, stream>>>(yv, sz, W_outT, out);
}